// Round 5
// baseline (312.537 us; speedup 1.0000x reference)
//
#include <hip/hip_runtime.h>
#include <cstdint>
#include <cstddef>

#define BDIM 2
#define NQ 512
#define NEXP 256
#define MDIM 768
#define HN 48
#define DD 16
#define ED 768

typedef short v8s __attribute__((ext_vector_type(8)));
typedef float v4f __attribute__((ext_vector_type(4)));

// ---------------------------------------------------------------------------
// prep: wve[h][k] = sum_d w_force[h*16+d] * Wv[(h*16+d)*E + k]
//       ube[h]    = sum_d w_force[h*16+d] * bv[h*16+d]
// ---------------------------------------------------------------------------
__global__ void prep_kernel(const float* __restrict__ Wv, const float* __restrict__ bv,
                            const float* __restrict__ wf,
                            float* __restrict__ wve, float* __restrict__ ube) {
  int h = blockIdx.x;
  float wl[DD];
#pragma unroll
  for (int d = 0; d < DD; ++d) wl[d] = wf[h * DD + d];
  for (int k = threadIdx.x; k < ED; k += blockDim.x) {
    float s = 0.f;
#pragma unroll
    for (int d = 0; d < DD; ++d) s = fmaf(wl[d], Wv[(size_t)(h * DD + d) * ED + k], s);
    wve[(size_t)h * ED + k] = s;
  }
  if (threadIdx.x == 0) {
    float s = 0.f;
#pragma unroll
    for (int d = 0; d < DD; ++d) s = fmaf(wl[d], bv[h * DD + d], s);
    ube[h] = s;
  }
}

// ---------------------------------------------------------------------------
// convert: fp32 -> bf16 (RNE). A = query (1024x768). B = [Wq;Wk;wve] padded
// to 1600 rows x 768 (rows >=1584 zeroed; their GEMM outputs are never stored).
// ---------------------------------------------------------------------------
__global__ __launch_bounds__(256) void convert_kernel(
    const float* __restrict__ query, const float* __restrict__ Wq,
    const float* __restrict__ Wk, const float* __restrict__ wve,
    ushort* __restrict__ Abf, ushort* __restrict__ Bbf) {
  const int id = blockIdx.x * 256 + threadIdx.x;   // 984*256 = 251904 exact
  const float* src = nullptr;
  ushort* dst;
  if (id < 98304) {                   // A: 786432/8 chunks
    const int off = id * 8;
    src = query + off;
    dst = Abf + off;
  } else {
    const int id2 = id - 98304;       // < 153600
    const int r = id2 / 96;
    const int k = (id2 - r * 96) * 8;
    dst = Bbf + (size_t)r * 768 + k;
    if (r < 768)       src = Wq + (size_t)r * 768 + k;
    else if (r < 1536) src = Wk + (size_t)(r - 768) * 768 + k;
    else if (r < 1584) src = wve + (size_t)(r - 1536) * 768 + k;
  }
  union { ushort s[8]; uint4 v; } p;
  if (src) {
    const float4 v0 = *(const float4*)src;
    const float4 v1 = *(const float4*)(src + 4);
    const float vv[8] = {v0.x, v0.y, v0.z, v0.w, v1.x, v1.y, v1.z, v1.w};
#pragma unroll
    for (int i = 0; i < 8; ++i) {
      union { float f; uint32_t u; } c; c.f = vv[i];
      p.s[i] = (ushort)((c.u + 0x7FFFu + ((c.u >> 16) & 1u)) >> 16);
    }
  } else {
#pragma unroll
    for (int i = 0; i < 8; ++i) p.s[i] = 0;
  }
  *(uint4*)dst = p.v;
}

// ---------------------------------------------------------------------------
// proj_mfma: C[1024 x 1600] = A_bf16[1024x768] @ B_bf16[1600x768]^T via
// v_mfma_f32_16x16x32_bf16. Block 256 thr / 4 waves; tile 64x64; wave w owns
// rows [w*16,w*16+16) x 64 cols = 4 MFMA tiles. LDS fragments stored in the
// exact per-lane-16B order the wave consumes (conflict-free ds_read_b128).
// Epilogue scatter identical to the old fp32 proj:
//   c<768 -> qs (bias+scale), c<1536 -> ke transposed, c<1584 -> ub.
// A-frag: A[m=lane&15][k=(lane>>4)*8+j]; C/D: col=lane&15, row=(lane>>4)*4+reg
// (verified layouts, learn_hip m89/m91).
// ---------------------------------------------------------------------------
__global__ __launch_bounds__(256) void proj_mfma(
    const ushort* __restrict__ Abf, const ushort* __restrict__ Bbf,
    const float* __restrict__ bq, const float* __restrict__ bk,
    const float* __restrict__ ube,
    float* __restrict__ qs, float* __restrict__ ke, float* __restrict__ ub) {
  __shared__ __align__(16) ushort As[4][4][16][8];  // [wave][kgrp][m][j] 4 KB
  __shared__ __align__(16) ushort Bs[4][64][8];     // [kgrp][n][j]       4 KB
  const int tid = threadIdx.x;
  const int wave = tid >> 6, lane = tid & 63;
  const int m0 = blockIdx.y * 64, n0 = blockIdx.x * 64;
  const int arow = tid >> 2;    // 0..63
  const int aseg = tid & 3;     // k-group 0..3
  v4f acc[4] = {v4f{0,0,0,0}, v4f{0,0,0,0}, v4f{0,0,0,0}, v4f{0,0,0,0}};

  for (int k0 = 0; k0 < ED; k0 += 32) {
    __syncthreads();
    *(uint4*)&As[arow >> 4][aseg][arow & 15][0] =
        *(const uint4*)&Abf[(size_t)(m0 + arow) * ED + k0 + aseg * 8];
    *(uint4*)&Bs[aseg][arow][0] =
        *(const uint4*)&Bbf[(size_t)(n0 + arow) * ED + k0 + aseg * 8];
    __syncthreads();
    const v8s af = *(const v8s*)&As[wave][lane >> 4][lane & 15][0];
#pragma unroll
    for (int nt = 0; nt < 4; ++nt) {
      const v8s bfr = *(const v8s*)&Bs[lane >> 4][nt * 16 + (lane & 15)][0];
      acc[nt] = __builtin_amdgcn_mfma_f32_16x16x32_bf16(af, bfr, acc[nt], 0, 0, 0);
    }
  }

#pragma unroll
  for (int nt = 0; nt < 4; ++nt) {
    const int c = n0 + nt * 16 + (lane & 15);
    if (c >= 1584) continue;
#pragma unroll
    for (int r = 0; r < 4; ++r) {
      const int row = m0 + wave * 16 + (lane >> 4) * 4 + r;
      const int b = row >> 9, n = row & 511;
      const float val = acc[nt][r];
      if (c < 768) {
        qs[(size_t)(b * NQ + n) * ED + c] = (val + bq[c]) * 0.25f;
      } else if (c < 1536) {
        const int ck = c - 768;
        const int hh = ck >> 4, dd = ck & 15;
        ke[(size_t)((b * HN + hh) * DD + dd) * MDIM + n] = val + bk[ck];
      } else {
        const int hh = c - 1536;
        ub[(size_t)(b * HN + hh) * MDIM + n] = val + ube[hh];
      }
    }
  }
}

// ---------------------------------------------------------------------------
// gather: fill m in [512,768) of ke / ub via outcell_index
// ---------------------------------------------------------------------------
__global__ void gather_kernel(const int* __restrict__ idx, float* __restrict__ ke,
                              float* __restrict__ ub) {
  const int id = blockIdx.x * 256 + threadIdx.x;
  const int N1 = BDIM * HN * DD * NEXP;  // 393216
  if (id < N1) {
    int j = id & (NEXP - 1);
    int d = (id >> 8) & (DD - 1);
    int hb = id >> 12;                   // b*48 + h, 0..95
    int n = idx[(hb / HN) * NEXP + j];
    float* row = ke + (size_t)(hb * DD + d) * MDIM;
    row[NQ + j] = row[n];
  } else {
    int id2 = id - N1;
    if (id2 < BDIM * HN * NEXP) {
      int j = id2 & (NEXP - 1);
      int hb = id2 >> 8;                 // b*48 + h
      int n = idx[(hb / HN) * NEXP + j];
      float* row = ub + (size_t)hb * MDIM;
      row[NQ + j] = row[n];
    }
  }
}

// ---------------------------------------------------------------------------
// fused attention v4 (LDS-K, 8 rows/block): v3 measured ~85us (fell below the
// 89us harness fill in top-5). v3 residual theory: (1) 1024 blocks @ 3/CU ->
// 256-block tail at 1/3 utilization; (2) K staged 128x per head (600 MB L2
// traffic); (3) each wave's 48KB LDS read served ONE q-row.
// v4: block = (b, hg, 8 q-rows), wave = 2 rows x 12 heads. Grid 512 = exactly
// 2 blocks/CU resident (LDS 48KB allows 3) -> zero tail; K-stage traffic
// halves (300 MB); each K ds_read feeds BOTH rows' FMAs. Persistent state
// a[2][3]+wacc[2][3]=48 VGPR, expect ~140 total - no launch-bounds forcing
// (rounds 1-2: forcing below scheduler demand = wholesale spill).
// Bias deep-prefetch per row retained; FP order identical to v3 (same
// d-order, same softmax) -> absmax unchanged.
// ---------------------------------------------------------------------------
__device__ __forceinline__ void fma4(float4& a, float q, const float4& k) {
  a.x = fmaf(q, k.x, a.x); a.y = fmaf(q, k.y, a.y);
  a.z = fmaf(q, k.z, a.z); a.w = fmaf(q, k.w, a.w);
}

__global__ __launch_bounds__(256) void fused_kernel(
    const float* __restrict__ qs, const float* __restrict__ ke, const float* __restrict__ ub,
    const float* __restrict__ bias, float* __restrict__ Wp) {
  __shared__ __align__(16) float Ks[DD * MDIM];   // 48 KB: K[d][m] for one head
  const int bid = blockIdx.x;                     // 512 blocks
  const int b = bid & 1;
  const int hg = (bid >> 1) & 3;
  const int n0 = (bid >> 3) * 8;
  const int wave = threadIdx.x >> 6;
  const int lane = threadIdx.x & 63;
  const int r0 = n0 + wave * 2;       // this wave's two query rows: r0, r0+1
  const int hbase = hg * 12;

  float4 wacc[2][3] = {};  // per-row W partial over the 12 heads (768 cols)
  float4 a[2][3];          // bias prefetch -> score accumulator

  // prefetch first head's bias rows
#pragma unroll
  for (int qi = 0; qi < 2; ++qi) {
    const float4* bp = (const float4*)(bias + (size_t)((b * HN + hbase) * NQ + r0 + qi) * MDIM);
#pragma unroll
    for (int j = 0; j < 3; ++j) a[qi][j] = bp[lane + 64 * j];
  }

  for (int hi = 0; hi < 12; ++hi) {
    const int h = hbase + hi;

    // cooperative stage of K[h] (16x768 f32, contiguous) into LDS
    __syncthreads();   // protect previous head's Ks readers
    {
      const float4* src = (const float4*)(ke + (size_t)(b * HN + h) * DD * MDIM);
      float4* dst = (float4*)Ks;
#pragma unroll
      for (int it = 0; it < 12; ++it)
        dst[it * 256 + threadIdx.x] = src[it * 256 + threadIdx.x];
    }
    __syncthreads();

    // u row for this head (L2-hot)
    const float4* u4 = (const float4*)(ub + (size_t)(b * HN + h) * MDIM);
    const float4 u0 = u4[lane], u1 = u4[lane + 64], u2 = u4[lane + 128];

    // q: 16 floats per row, wave-uniform
    const float4* qp0 = (const float4*)(qs + (size_t)(b * NQ + r0) * ED + h * DD);
    const float4* qp1 = (const float4*)(qs + (size_t)(b * NQ + r0 + 1) * ED + h * DD);

    // scores: a (holds prefetched bias) += q_d * K_lds[d][m]; each K read
    // feeds BOTH rows
    const float4* kl = (const float4*)Ks;
#pragma unroll
    for (int d4 = 0; d4 < 4; ++d4) {
      const float4 qv0 = qp0[d4];
      const float4 qv1 = qp1[d4];
#pragma unroll
      for (int dd = 0; dd < 4; ++dd) {
        const int d = d4 * 4 + dd;
        const float4 k0 = kl[d * 192 + lane];
        const float4 k1 = kl[d * 192 + lane + 64];
        const float4 k2 = kl[d * 192 + lane + 128];
        const float qd0 = (dd == 0) ? qv0.x : (dd == 1) ? qv0.y : (dd == 2) ? qv0.z : qv0.w;
        const float qd1 = (dd == 0) ? qv1.x : (dd == 1) ? qv1.y : (dd == 2) ? qv1.z : qv1.w;
        fma4(a[0][0], qd0, k0); fma4(a[0][1], qd0, k1); fma4(a[0][2], qd0, k2);
        fma4(a[1][0], qd1, k0); fma4(a[1][1], qd1, k1); fma4(a[1][2], qd1, k2);
      }
    }

    // softmax + PV per row (12 vals/lane x 64 lanes = full 768)
#pragma unroll
    for (int qi = 0; qi < 2; ++qi) {
      float mx = -1e30f;
#pragma unroll
      for (int j = 0; j < 3; ++j)
        mx = fmaxf(mx, fmaxf(fmaxf(a[qi][j].x, a[qi][j].y), fmaxf(a[qi][j].z, a[qi][j].w)));
#pragma unroll
      for (int sh = 32; sh > 0; sh >>= 1) mx = fmaxf(mx, __shfl_xor(mx, sh));
      float e[12];
#pragma unroll
      for (int j = 0; j < 3; ++j) {
        e[j * 4 + 0] = __expf(a[qi][j].x - mx);
        e[j * 4 + 1] = __expf(a[qi][j].y - mx);
        e[j * 4 + 2] = __expf(a[qi][j].z - mx);
        e[j * 4 + 3] = __expf(a[qi][j].w - mx);
      }
      // a[qi] is dead now: prefetch next head's bias row qi (hides HBM
      // latency under the sum-reduce + PV + next K-stage)
      if (hi < 11) {
        const float4* bp = (const float4*)(bias + (size_t)((b * HN + h + 1) * NQ + r0 + qi) * MDIM);
#pragma unroll
        for (int j = 0; j < 3; ++j) a[qi][j] = bp[lane + 64 * j];
      }
      float l = 0.f;
#pragma unroll
      for (int k = 0; k < 12; ++k) l += e[k];
#pragma unroll
      for (int sh = 32; sh > 0; sh >>= 1) l += __shfl_xor(l, sh);
      const float inv = 1.0f / l;
#pragma unroll
      for (int j = 0; j < 3; ++j) {
        const float4 uu = (j == 0) ? u0 : (j == 1) ? u1 : u2;
        wacc[qi][j].x = fmaf(e[j * 4 + 0] * inv, uu.x, wacc[qi][j].x);
        wacc[qi][j].y = fmaf(e[j * 4 + 1] * inv, uu.y, wacc[qi][j].y);
        wacc[qi][j].z = fmaf(e[j * 4 + 2] * inv, uu.z, wacc[qi][j].z);
        wacc[qi][j].w = fmaf(e[j * 4 + 3] * inv, uu.w, wacc[qi][j].w);
      }
    }
  }

  // write both (row, hg) partials directly (no cross-wave reduce needed)
  float4* wp = (float4*)Wp;
#pragma unroll
  for (int qi = 0; qi < 2; ++qi)
#pragma unroll
    for (int j = 0; j < 3; ++j)
      wp[((size_t)(b * NQ + r0 + qi) * 4 + hg) * 192 + lane + 64 * j] = wacc[qi][j];
}

// ---------------------------------------------------------------------------
// force: sum the 4 hg-partials of W, then force[row,c] = sum_m W*dp.
// One wave per (b,n) row.
// ---------------------------------------------------------------------------
__global__ __launch_bounds__(256) void force_kernel(
    const float* __restrict__ Wp, const float* __restrict__ dp, float* __restrict__ out) {
  const int wave = threadIdx.x >> 6;
  const int lane = threadIdx.x & 63;
  const int row = blockIdx.x * 4 + wave;     // 0..1023 == b*512+n
  const float4* wp = (const float4*)Wp;
  float4 ws[3];
#pragma unroll
  for (int j = 0; j < 3; ++j) {
    float4 s = wp[((size_t)row * 4 + 0) * 192 + lane + 64 * j];
#pragma unroll
    for (int hg = 1; hg < 4; ++hg) {
      const float4 t = wp[((size_t)row * 4 + hg) * 192 + lane + 64 * j];
      s.x += t.x; s.y += t.y; s.z += t.z; s.w += t.w;
    }
    ws[j] = s;
  }
  const float* dpp = dp + (size_t)row * MDIM * 3;
  float f0 = 0.f, f1 = 0.f, f2 = 0.f;
#pragma unroll
  for (int j = 0; j < 3; ++j) {
    const float4 w = ws[j];
    const int m0 = j * 256 + lane * 4;
    const float4* dv = (const float4*)(dpp + (size_t)m0 * 3);
    const float4 d0 = dv[0], d1 = dv[1], d2 = dv[2];
    f0 = fmaf(w.x, d0.x, f0); f0 = fmaf(w.y, d0.w, f0); f0 = fmaf(w.z, d1.z, f0); f0 = fmaf(w.w, d2.y, f0);
    f1 = fmaf(w.x, d0.y, f1); f1 = fmaf(w.y, d1.x, f1); f1 = fmaf(w.z, d1.w, f1); f1 = fmaf(w.w, d2.z, f1);
    f2 = fmaf(w.x, d0.z, f2); f2 = fmaf(w.y, d1.y, f2); f2 = fmaf(w.z, d2.x, f2); f2 = fmaf(w.w, d2.w, f2);
  }
#pragma unroll
  for (int sh = 32; sh > 0; sh >>= 1) {
    f0 += __shfl_xor(f0, sh);
    f1 += __shfl_xor(f1, sh);
    f2 += __shfl_xor(f2, sh);
  }
  if (lane == 0) {
    float* op = out + (size_t)row * 3;
    op[0] = f0; op[1] = f1; op[2] = f2;
  }
}

// ---------------------------------------------------------------------------
extern "C" void kernel_launch(void* const* d_in, const int* in_sizes, int n_in,
                              void* d_out, int out_size, void* d_ws, size_t ws_size,
                              hipStream_t stream) {
  const float* query     = (const float*)d_in[0];
  const float* attn_bias = (const float*)d_in[1];
  const float* delta_pos = (const float*)d_in[2];
  const int*   outcell   = (const int*)d_in[3];
  const float* Wq = (const float*)d_in[4];
  const float* bq = (const float*)d_in[5];
  const float* Wk = (const float*)d_in[6];
  const float* bk = (const float*)d_in[7];
  const float* Wv = (const float*)d_in[8];
  const float* bv = (const float*)d_in[9];
  const float* wf = (const float*)d_in[10];
  float* out = (float*)d_out;
  float* ws  = (float*)d_ws;

  // workspace layout (float offsets, all 16B-aligned): total 6,230,080 fl ~ 24.9 MB
  float* wve  = ws;                       // 36864
  float* ube  = ws + 36864;               // 64
  float* qsb  = ws + 36928;               // 786432
  float* keb  = ws + 823360;              // 1179648
  float* ubb  = ws + 2003008;             // 73728
  float* Wpb  = ws + 2076736;             // 3145728
  ushort* Abf = (ushort*)(ws + 5222464);  // 786432 bf16
  ushort* Bbf = (ushort*)(ws + 5615680);  // 1228800 bf16 (1600x768)

  prep_kernel<<<HN, 256, 0, stream>>>(Wv, bv, wf, wve, ube);
  convert_kernel<<<984, 256, 0, stream>>>(query, Wq, Wk, wve, Abf, Bbf);
  proj_mfma<<<dim3(25, 16), 256, 0, stream>>>(Abf, Bbf, bq, bk, ube, qsb, keb, ubb);
  gather_kernel<<<1632, 256, 0, stream>>>(outcell, keb, ubb);
  fused_kernel<<<512, 256, 0, stream>>>(qsb, keb, ubb, attn_bias, Wpb);
  force_kernel<<<256, 256, 0, stream>>>(Wpb, delta_pos, out);
}

// Round 6
// 292.915 us; speedup vs baseline: 1.0670x; 1.0670x over previous
//
#include <hip/hip_runtime.h>
#include <cstdint>
#include <cstddef>

#define BDIM 2
#define NQ 512
#define NEXP 256
#define MDIM 768
#define HN 48
#define DD 16
#define ED 768

typedef short v8s __attribute__((ext_vector_type(8)));
typedef float v4f __attribute__((ext_vector_type(4)));

// ---------------------------------------------------------------------------
// prep: wve[h][k] = sum_d w_force[h*16+d] * Wv[(h*16+d)*E + k]
//       ube[h]    = sum_d w_force[h*16+d] * bv[h*16+d]
// ---------------------------------------------------------------------------
__global__ void prep_kernel(const float* __restrict__ Wv, const float* __restrict__ bv,
                            const float* __restrict__ wf,
                            float* __restrict__ wve, float* __restrict__ ube) {
  int h = blockIdx.x;
  float wl[DD];
#pragma unroll
  for (int d = 0; d < DD; ++d) wl[d] = wf[h * DD + d];
  for (int k = threadIdx.x; k < ED; k += blockDim.x) {
    float s = 0.f;
#pragma unroll
    for (int d = 0; d < DD; ++d) s = fmaf(wl[d], Wv[(size_t)(h * DD + d) * ED + k], s);
    wve[(size_t)h * ED + k] = s;
  }
  if (threadIdx.x == 0) {
    float s = 0.f;
#pragma unroll
    for (int d = 0; d < DD; ++d) s = fmaf(wl[d], bv[h * DD + d], s);
    ube[h] = s;
  }
}

// ---------------------------------------------------------------------------
// convert: fp32 -> bf16 (RNE). A = query (1024x768). B = [Wq;Wk;wve] padded
// to 1600 rows x 768 (rows >=1584 zeroed; their GEMM outputs are never stored).
// ---------------------------------------------------------------------------
__global__ __launch_bounds__(256) void convert_kernel(
    const float* __restrict__ query, const float* __restrict__ Wq,
    const float* __restrict__ Wk, const float* __restrict__ wve,
    ushort* __restrict__ Abf, ushort* __restrict__ Bbf) {
  const int id = blockIdx.x * 256 + threadIdx.x;   // 984*256 = 251904 exact
  const float* src = nullptr;
  ushort* dst;
  if (id < 98304) {                   // A: 786432/8 chunks
    const int off = id * 8;
    src = query + off;
    dst = Abf + off;
  } else {
    const int id2 = id - 98304;       // < 153600
    const int r = id2 / 96;
    const int k = (id2 - r * 96) * 8;
    dst = Bbf + (size_t)r * 768 + k;
    if (r < 768)       src = Wq + (size_t)r * 768 + k;
    else if (r < 1536) src = Wk + (size_t)(r - 768) * 768 + k;
    else if (r < 1584) src = wve + (size_t)(r - 1536) * 768 + k;
  }
  union { ushort s[8]; uint4 v; } p;
  if (src) {
    const float4 v0 = *(const float4*)src;
    const float4 v1 = *(const float4*)(src + 4);
    const float vv[8] = {v0.x, v0.y, v0.z, v0.w, v1.x, v1.y, v1.z, v1.w};
#pragma unroll
    for (int i = 0; i < 8; ++i) {
      union { float f; uint32_t u; } c; c.f = vv[i];
      p.s[i] = (ushort)((c.u + 0x7FFFu + ((c.u >> 16) & 1u)) >> 16);
    }
  } else {
#pragma unroll
    for (int i = 0; i < 8; ++i) p.s[i] = 0;
  }
  *(uint4*)dst = p.v;
}

// ---------------------------------------------------------------------------
// proj_mfma: C[1024 x 1600] = A_bf16[1024x768] @ B_bf16[1600x768]^T via
// v_mfma_f32_16x16x32_bf16. Block 256 thr / 4 waves; tile 64x64; wave w owns
// rows [w*16,w*16+16) x 64 cols = 4 MFMA tiles. LDS fragments stored in the
// exact per-lane-16B order the wave consumes (conflict-free ds_read_b128).
// Epilogue scatter identical to the old fp32 proj:
//   c<768 -> qs (bias+scale), c<1536 -> ke transposed, c<1584 -> ub.
// A-frag: A[m=lane&15][k=(lane>>4)*8+j]; C/D: col=lane&15, row=(lane>>4)*4+reg
// (verified layouts, learn_hip m89/m91).
// ---------------------------------------------------------------------------
__global__ __launch_bounds__(256) void proj_mfma(
    const ushort* __restrict__ Abf, const ushort* __restrict__ Bbf,
    const float* __restrict__ bq, const float* __restrict__ bk,
    const float* __restrict__ ube,
    float* __restrict__ qs, float* __restrict__ ke, float* __restrict__ ub) {
  __shared__ __align__(16) ushort As[4][4][16][8];  // [wave][kgrp][m][j] 4 KB
  __shared__ __align__(16) ushort Bs[4][64][8];     // [kgrp][n][j]       4 KB
  const int tid = threadIdx.x;
  const int wave = tid >> 6, lane = tid & 63;
  const int m0 = blockIdx.y * 64, n0 = blockIdx.x * 64;
  const int arow = tid >> 2;    // 0..63
  const int aseg = tid & 3;     // k-group 0..3
  v4f acc[4] = {v4f{0,0,0,0}, v4f{0,0,0,0}, v4f{0,0,0,0}, v4f{0,0,0,0}};

  for (int k0 = 0; k0 < ED; k0 += 32) {
    __syncthreads();
    *(uint4*)&As[arow >> 4][aseg][arow & 15][0] =
        *(const uint4*)&Abf[(size_t)(m0 + arow) * ED + k0 + aseg * 8];
    *(uint4*)&Bs[aseg][arow][0] =
        *(const uint4*)&Bbf[(size_t)(n0 + arow) * ED + k0 + aseg * 8];
    __syncthreads();
    const v8s af = *(const v8s*)&As[wave][lane >> 4][lane & 15][0];
#pragma unroll
    for (int nt = 0; nt < 4; ++nt) {
      const v8s bfr = *(const v8s*)&Bs[lane >> 4][nt * 16 + (lane & 15)][0];
      acc[nt] = __builtin_amdgcn_mfma_f32_16x16x32_bf16(af, bfr, acc[nt], 0, 0, 0);
    }
  }

#pragma unroll
  for (int nt = 0; nt < 4; ++nt) {
    const int c = n0 + nt * 16 + (lane & 15);
    if (c >= 1584) continue;
#pragma unroll
    for (int r = 0; r < 4; ++r) {
      const int row = m0 + wave * 16 + (lane >> 4) * 4 + r;
      const int b = row >> 9, n = row & 511;
      const float val = acc[nt][r];
      if (c < 768) {
        qs[(size_t)(b * NQ + n) * ED + c] = (val + bq[c]) * 0.25f;
      } else if (c < 1536) {
        const int ck = c - 768;
        const int hh = ck >> 4, dd = ck & 15;
        ke[(size_t)((b * HN + hh) * DD + dd) * MDIM + n] = val + bk[ck];
      } else {
        const int hh = c - 1536;
        ub[(size_t)(b * HN + hh) * MDIM + n] = val + ube[hh];
      }
    }
  }
}

// ---------------------------------------------------------------------------
// gather: fill m in [512,768) of ke / ub via outcell_index
// ---------------------------------------------------------------------------
__global__ void gather_kernel(const int* __restrict__ idx, float* __restrict__ ke,
                              float* __restrict__ ub) {
  const int id = blockIdx.x * 256 + threadIdx.x;
  const int N1 = BDIM * HN * DD * NEXP;  // 393216
  if (id < N1) {
    int j = id & (NEXP - 1);
    int d = (id >> 8) & (DD - 1);
    int hb = id >> 12;                   // b*48 + h, 0..95
    int n = idx[(hb / HN) * NEXP + j];
    float* row = ke + (size_t)(hb * DD + d) * MDIM;
    row[NQ + j] = row[n];
  } else {
    int id2 = id - N1;
    if (id2 < BDIM * HN * NEXP) {
      int j = id2 & (NEXP - 1);
      int hb = id2 >> 8;                 // b*48 + h
      int n = idx[(hb / HN) * NEXP + j];
      float* row = ub + (size_t)hb * MDIM;
      row[NQ + j] = row[n];
    }
  }
}

// ---------------------------------------------------------------------------
// fused attention v5 (half-staged LDS-K, occupancy-focused).
// Round-5 post-mortem: time tracks resident waves/CU (8w->104us, 12w->84,
// 8w->101). v3 was capped at 12 waves/CU by BOTH LDS (48KB -> 3 blk/CU) and
// VGPR (160). v5 keeps v3's shape (grid 1024, wave = 1 row x 12 heads) and
// raises the cap on both axes:
//   - K staged per head in TWO 8-d-row halves -> LDS 24KB (6 blk/CU by LDS);
//     4 barriers/head instead of 2.
//   - staging via __builtin_amdgcn_global_load_lds width=16 (no VGPR
//     round-trip, dest linear in exact lane order - guide Sec.5);
//   - exp computed IN PLACE in a[] (drops e[12] regs; identical FP order:
//     same exps, same sum order, same PV order -> absmax unchanged);
//   - q loaded per half (8 regs, not 16).
// Natural VGPR estimate ~90-110 -> 4-5 waves/SIMD; NO launch-bounds forcing
// (rounds 1-2: forcing below scheduler demand = wholesale scratch spill).
// Bias deep-prefetch retained (a[] refilled right after PV consumes it).
// ---------------------------------------------------------------------------
__device__ __forceinline__ void fma4(float4& a, float q, const float4& k) {
  a.x = fmaf(q, k.x, a.x); a.y = fmaf(q, k.y, a.y);
  a.z = fmaf(q, k.z, a.z); a.w = fmaf(q, k.w, a.w);
}

__device__ __forceinline__ void gload_lds16(const float4* g, float4* l) {
  __builtin_amdgcn_global_load_lds(
      (const __attribute__((address_space(1))) void*)g,
      (__attribute__((address_space(3))) void*)l, 16, 0, 0);
}

__global__ __launch_bounds__(256) void fused_kernel(
    const float* __restrict__ qs, const float* __restrict__ ke, const float* __restrict__ ub,
    const float* __restrict__ bias, float* __restrict__ Wp) {
  __shared__ __align__(16) float Ks[8 * MDIM];    // 24 KB: half-head K (8 d-rows)
  const int bid = blockIdx.x;                     // 1024 blocks
  const int b = bid & 1;
  const int hg = (bid >> 1) & 3;
  const int n0 = (bid >> 3) * 4;
  const int wave = threadIdx.x >> 6;
  const int lane = threadIdx.x & 63;
  const int r = n0 + wave;            // this wave's query row
  const int hbase = hg * 12;

  float4 wacc[3] = {};   // this row's W partial over the 12 heads (768 cols)
  float4 a[3];           // bias prefetch -> scores -> (in-place) exp

  // prefetch first head's bias row
  {
    const float4* bp = (const float4*)(bias + (size_t)((b * HN + hbase) * NQ + r) * MDIM);
#pragma unroll
    for (int j = 0; j < 3; ++j) a[j] = bp[lane + 64 * j];
  }

  for (int hi = 0; hi < 12; ++hi) {
    const int h = hbase + hi;
    const float4* qp4 = (const float4*)(qs + (size_t)(b * NQ + r) * ED + h * DD);
    const float4* kl = (const float4*)Ks;

    // scores in two d-halves; K half staged to LDS via global_load_lds
#pragma unroll
    for (int dh = 0; dh < 2; ++dh) {
      __syncthreads();   // protect previous half's readers
      {
        const float4* src = (const float4*)(ke + ((size_t)(b * HN + h) * DD + dh * 8) * MDIM);
        float4* dstb = (float4*)Ks;
#pragma unroll
        for (int it = 0; it < 6; ++it) {
          const int base = (it * 4 + wave) * 64;   // wave-uniform float4 index
          gload_lds16(src + base + lane, dstb + base);
        }
      }
      __syncthreads();   // vmcnt(0) drained before barrier -> Ks valid

      const float4 q0 = qp4[dh * 2], q1 = qp4[dh * 2 + 1];
#pragma unroll
      for (int d4 = 0; d4 < 2; ++d4) {
        const float4 qv = d4 ? q1 : q0;
#pragma unroll
        for (int dd = 0; dd < 4; ++dd) {
          const int d = d4 * 4 + dd;               // local d 0..7
          const float4 k0 = kl[d * 192 + lane];
          const float4 k1 = kl[d * 192 + lane + 64];
          const float4 k2 = kl[d * 192 + lane + 128];
          const float qd = (dd == 0) ? qv.x : (dd == 1) ? qv.y : (dd == 2) ? qv.z : qv.w;
          fma4(a[0], qd, k0);
          fma4(a[1], qd, k1);
          fma4(a[2], qd, k2);
        }
      }
    }

    // u row for this head (small, L2-hot)
    const float4* u4 = (const float4*)(ub + (size_t)(b * HN + h) * MDIM);
    const float4 u0 = u4[lane], u1 = u4[lane + 64], u2 = u4[lane + 128];

    // softmax over the full 768-row (12 vals/lane x 64 lanes), exp IN PLACE
    float mx = -1e30f;
#pragma unroll
    for (int j = 0; j < 3; ++j)
      mx = fmaxf(mx, fmaxf(fmaxf(a[j].x, a[j].y), fmaxf(a[j].z, a[j].w)));
#pragma unroll
    for (int sh = 32; sh > 0; sh >>= 1) mx = fmaxf(mx, __shfl_xor(mx, sh));
#pragma unroll
    for (int j = 0; j < 3; ++j) {
      a[j].x = __expf(a[j].x - mx);
      a[j].y = __expf(a[j].y - mx);
      a[j].z = __expf(a[j].z - mx);
      a[j].w = __expf(a[j].w - mx);
    }
    float l = 0.f;
#pragma unroll
    for (int j = 0; j < 3; ++j) { l += a[j].x; l += a[j].y; l += a[j].z; l += a[j].w; }
#pragma unroll
    for (int sh = 32; sh > 0; sh >>= 1) l += __shfl_xor(l, sh);
    const float inv = 1.0f / l;
#pragma unroll
    for (int j = 0; j < 3; ++j) {
      const float4 uu = (j == 0) ? u0 : (j == 1) ? u1 : u2;
      wacc[j].x = fmaf(a[j].x * inv, uu.x, wacc[j].x);
      wacc[j].y = fmaf(a[j].y * inv, uu.y, wacc[j].y);
      wacc[j].z = fmaf(a[j].z * inv, uu.z, wacc[j].z);
      wacc[j].w = fmaf(a[j].w * inv, uu.w, wacc[j].w);
    }

    // a[] is dead now: prefetch next head's bias row (in flight across the
    // next head's two staging barriers + score phase)
    if (hi < 11) {
      const float4* bp = (const float4*)(bias + (size_t)((b * HN + h + 1) * NQ + r) * MDIM);
#pragma unroll
      for (int j = 0; j < 3; ++j) a[j] = bp[lane + 64 * j];
    }
  }

  // write this (row, hg) partial directly (no cross-wave reduce needed)
  float4* wp = (float4*)Wp;
#pragma unroll
  for (int j = 0; j < 3; ++j)
    wp[((size_t)(b * NQ + r) * 4 + hg) * 192 + lane + 64 * j] = wacc[j];
}

// ---------------------------------------------------------------------------
// force: sum the 4 hg-partials of W, then force[row,c] = sum_m W*dp.
// One wave per (b,n) row.
// ---------------------------------------------------------------------------
__global__ __launch_bounds__(256) void force_kernel(
    const float* __restrict__ Wp, const float* __restrict__ dp, float* __restrict__ out) {
  const int wave = threadIdx.x >> 6;
  const int lane = threadIdx.x & 63;
  const int row = blockIdx.x * 4 + wave;     // 0..1023 == b*512+n
  const float4* wp = (const float4*)Wp;
  float4 ws[3];
#pragma unroll
  for (int j = 0; j < 3; ++j) {
    float4 s = wp[((size_t)row * 4 + 0) * 192 + lane + 64 * j];
#pragma unroll
    for (int hg = 1; hg < 4; ++hg) {
      const float4 t = wp[((size_t)row * 4 + hg) * 192 + lane + 64 * j];
      s.x += t.x; s.y += t.y; s.z += t.z; s.w += t.w;
    }
    ws[j] = s;
  }
  const float* dpp = dp + (size_t)row * MDIM * 3;
  float f0 = 0.f, f1 = 0.f, f2 = 0.f;
#pragma unroll
  for (int j = 0; j < 3; ++j) {
    const float4 w = ws[j];
    const int m0 = j * 256 + lane * 4;
    const float4* dv = (const float4*)(dpp + (size_t)m0 * 3);
    const float4 d0 = dv[0], d1 = dv[1], d2 = dv[2];
    f0 = fmaf(w.x, d0.x, f0); f0 = fmaf(w.y, d0.w, f0); f0 = fmaf(w.z, d1.z, f0); f0 = fmaf(w.w, d2.y, f0);
    f1 = fmaf(w.x, d0.y, f1); f1 = fmaf(w.y, d1.x, f1); f1 = fmaf(w.z, d1.w, f1); f1 = fmaf(w.w, d2.z, f1);
    f2 = fmaf(w.x, d0.z, f2); f2 = fmaf(w.y, d1.y, f2); f2 = fmaf(w.z, d2.x, f2); f2 = fmaf(w.w, d2.w, f2);
  }
#pragma unroll
  for (int sh = 32; sh > 0; sh >>= 1) {
    f0 += __shfl_xor(f0, sh);
    f1 += __shfl_xor(f1, sh);
    f2 += __shfl_xor(f2, sh);
  }
  if (lane == 0) {
    float* op = out + (size_t)row * 3;
    op[0] = f0; op[1] = f1; op[2] = f2;
  }
}

// ---------------------------------------------------------------------------
extern "C" void kernel_launch(void* const* d_in, const int* in_sizes, int n_in,
                              void* d_out, int out_size, void* d_ws, size_t ws_size,
                              hipStream_t stream) {
  const float* query     = (const float*)d_in[0];
  const float* attn_bias = (const float*)d_in[1];
  const float* delta_pos = (const float*)d_in[2];
  const int*   outcell   = (const int*)d_in[3];
  const float* Wq = (const float*)d_in[4];
  const float* bq = (const float*)d_in[5];
  const float* Wk = (const float*)d_in[6];
  const float* bk = (const float*)d_in[7];
  const float* Wv = (const float*)d_in[8];
  const float* bv = (const float*)d_in[9];
  const float* wf = (const float*)d_in[10];
  float* out = (float*)d_out;
  float* ws  = (float*)d_ws;

  // workspace layout (float offsets, all 16B-aligned): total 6,230,080 fl ~ 24.9 MB
  float* wve  = ws;                       // 36864
  float* ube  = ws + 36864;               // 64
  float* qsb  = ws + 36928;               // 786432
  float* keb  = ws + 823360;              // 1179648
  float* ubb  = ws + 2003008;             // 73728
  float* Wpb  = ws + 2076736;             // 3145728
  ushort* Abf = (ushort*)(ws + 5222464);  // 786432 bf16
  ushort* Bbf = (ushort*)(ws + 5615680);  // 1228800 bf16 (1600x768)

  prep_kernel<<<HN, 256, 0, stream>>>(Wv, bv, wf, wve, ube);
  convert_kernel<<<984, 256, 0, stream>>>(query, Wq, Wk, wve, Abf, Bbf);
  proj_mfma<<<dim3(25, 16), 256, 0, stream>>>(Abf, Bbf, bq, bk, ube, qsb, keb, ubb);
  gather_kernel<<<1632, 256, 0, stream>>>(outcell, keb, ubb);
  fused_kernel<<<1024, 256, 0, stream>>>(qsb, keb, ubb, attn_bias, Wpb);
  force_kernel<<<256, 256, 0, stream>>>(Wpb, delta_pos, out);
}